// Round 2
// baseline (123.809 us; speedup 1.0000x reference)
//
#include <hip/hip_runtime.h>
#include <math.h>

#define N_ATOMS 131072
#define N_MOLS  4096
#define DFEAT   128
#define NK      11
#define KDIM3   384          // 3 * DFEAT: [Sr | Sxr | Sxxr] blocks
#define N_DEPTH 128
#define EPS_F   1e-7f

__constant__ float c_means[NK] = {-1.645f, -1.08f, -0.739f, -0.468f, -0.228f,
                                  0.0f, 0.228f, 0.468f, 0.739f, 1.08f, 1.645f};
__constant__ float c_stds[NK]  = {0.283f, 0.17f, 0.134f, 0.118f, 0.114f,
                                  0.114f, 0.114f, 0.118f, 0.134f, 0.17f, 0.283f};

// Math: o_k(x) = 1 + a_k (x - m_k)^2,  a_k = 0.5 / (s_k^2 * log(s_k*sqrt(2pi))) < 0
// den(x) = sum_k o_k + EPS = C2 x^2 + C1 x + C0          (Horner, 2 fma)
// membership row: (o_k+EPS)*r = coef0(k)*r + coef1(k)*(x r) + coef2(k)*(x^2 r)
//   coef0 = (1+EPS) + a_k m_k^2, coef1 = -2 a_k m_k, coef2 = a_k
// segment-sum over atoms needs only Sr=sum r, Sxr=sum x r, Sxxr=sum x^2 r per (mol,d).
// mols @ W then becomes [4096 x 384] @ Bt[384 x 128] with Bt rows pre-folded from W.

// ---------------------------------------------------------------------------
// Kernel 1: (a) fold W into Bt[384][128]; (b) blocks >= 192 compute molecule
// offsets[0..4096] by binary search over the sorted atom_split.
// ---------------------------------------------------------------------------
__global__ __launch_bounds__(256) void wxform_offsets_kernel(
    const float* __restrict__ W,        // [DFEAT*NK, N_DEPTH]
    const int*   __restrict__ split,    // [N_ATOMS], sorted
    float*       __restrict__ Bt,       // [KDIM3, N_DEPTH]
    int*         __restrict__ offsets) {// [N_MOLS+1]
  const int bid = blockIdx.x;
  const int tid = threadIdx.x;
  if (bid < 192) {
    int t = bid * 256 + tid;            // 0..49151
    int n = t & 127;
    int row = t >> 7;                   // 0..383
    int j = row >> 7;                   // 0..2 (uniform per wave)
    int d = row & 127;
    float acc = 0.0f;
#pragma unroll
    for (int k = 0; k < NK; ++k) {
      float m = c_means[k], s = c_stds[k];
      float a = 0.5f / (s * s * logf(s * 2.5066282746310002f));
      float coef = (j == 2) ? a
                 : (j == 1) ? (-2.0f * a * m)
                            : fmaf(a, m * m, 1.0f + EPS_F);
      acc = fmaf(coef, W[(size_t)(d * NK + k) * N_DEPTH + n], acc);
    }
    Bt[(size_t)row * N_DEPTH + n] = acc;
  } else {
    int t = (bid - 192) * 256 + tid;    // 0..4351
    if (t <= N_MOLS) {
      // offsets[t] = lower_bound(split, t)
      int lo = 0, hi = N_ATOMS;
      while (lo < hi) { int mid = (lo + hi) >> 1; if (split[mid] < t) lo = mid + 1; else hi = mid; }
      offsets[t] = lo;
    }
  }
}

// ---------------------------------------------------------------------------
// Kernel 2: per-molecule block (256 threads = 8 atom-groups x 32 feature-quads).
// Accumulates Sr/Sxr/Sxxr per feature, LDS-reduces across the 8 groups, writes
// S[m][j*128+d] (j=0:Sr, 1:Sxr, 2:Sxxr). 7 VALU ops per (atom,feature).
// ---------------------------------------------------------------------------
__global__ __launch_bounds__(256) void memb_sums_kernel(
    const float* __restrict__ x,        // [N_ATOMS, DFEAT]
    const int*   __restrict__ offsets,  // [N_MOLS+1]
    float*       __restrict__ S) {      // [N_MOLS, KDIM3]
  const int m   = blockIdx.x;
  const int tid = threadIdx.x;
  const int fq  = tid & 31;             // feature quad: features fq*4..fq*4+3
  const int g   = tid >> 5;             // atom group 0..7

  // Horner coefficients for den = sum_k o_k + EPS
  float C2 = 0.0f, C1 = 0.0f, C0 = 11.0f + EPS_F;
#pragma unroll
  for (int k = 0; k < NK; ++k) {
    float m_ = c_means[k], s_ = c_stds[k];
    float a = 0.5f / (s_ * s_ * logf(s_ * 2.5066282746310002f));
    C2 += a;
    C1 = fmaf(-2.0f * a, m_, C1);
    C0 = fmaf(a, m_ * m_, C0);
  }

  const int start = offsets[m];
  const int end   = offsets[m + 1];

  float Sr[4]   = {0.f, 0.f, 0.f, 0.f};
  float Sxr[4]  = {0.f, 0.f, 0.f, 0.f};
  float Sxxr[4] = {0.f, 0.f, 0.f, 0.f};

  for (int a = start + g; a < end; a += 8) {
    float4 v = *(const float4*)&x[(size_t)a * DFEAT + fq * 4];
    float xv[4] = {v.x, v.y, v.z, v.w};
#pragma unroll
    for (int i = 0; i < 4; ++i) {
      float den = fmaf(fmaf(C2, xv[i], C1), xv[i], C0);
      float r   = __builtin_amdgcn_rcpf(den);   // den << 0 always; 1-ulp rcp
      float u   = xv[i] * r;
      Sr[i]  += r;
      Sxr[i] += u;
      Sxxr[i] = fmaf(xv[i], u, Sxxr[i]);
    }
  }

  __shared__ float red[8][32][13];      // 13: odd stride, conflict-light
#pragma unroll
  for (int i = 0; i < 4; ++i) {
    red[g][fq][i * 3 + 0] = Sr[i];
    red[g][fq][i * 3 + 1] = Sxr[i];
    red[g][fq][i * 3 + 2] = Sxxr[i];
  }
  __syncthreads();

  for (int t = tid; t < KDIM3; t += 256) {
    int j  = t >> 7;                    // component 0..2
    int f  = t & 127;                   // feature
    int q  = f >> 2, fi = f & 3;
    float s = 0.0f;
#pragma unroll
    for (int gg = 0; gg < 8; ++gg) s += red[gg][q][fi * 3 + j];
    S[(size_t)m * KDIM3 + t] = s;
  }
}

// ---------------------------------------------------------------------------
// Kernel 3: out[4096,128] = tanh(S[4096,384] @ Bt[384,128] + b)
// BM=8 rows/block, 512 blocks (2/CU), 256 threads: thread = (n0, g) computes
// rows {2g,2g+1} x cols {n0, n0+64}. A-panel in LDS (wave-uniform broadcast
// reads), Bt streamed from L2 (196 KB, resident). No split-K, fused epilogue.
// ---------------------------------------------------------------------------
#define GBM 8

__global__ __launch_bounds__(256) void gemm_bias_tanh_kernel(
    const float* __restrict__ A,        // [N_MOLS, KDIM3]
    const float* __restrict__ Bt,       // [KDIM3, N_DEPTH]
    const float* __restrict__ bias,     // [N_DEPTH]
    float*       __restrict__ out) {    // [N_MOLS, N_DEPTH]
  __shared__ float As[GBM][KDIM3];      // 12 KB
  const int tid = threadIdx.x;
  const int m0  = blockIdx.x * GBM;

  // Stage A rows: 8 x 384 floats = 768 float4, 3 per thread, coalesced,
  // contiguous LDS float4 writes (conflict-free).
#pragma unroll
  for (int i = 0; i < 3; ++i) {
    int idx = i * 256 + tid;            // 0..767
    int r   = idx / 96;
    int kf  = idx % 96;
    *(float4*)&As[r][kf * 4] = *(const float4*)&A[(size_t)(m0 + r) * KDIM3 + kf * 4];
  }
  __syncthreads();

  const int n0 = tid & 63;
  const int g  = tid >> 6;              // 0..3 (uniform per wave)
  const int r0 = 2 * g, r1 = 2 * g + 1;

  float acc00 = 0.f, acc01 = 0.f, acc10 = 0.f, acc11 = 0.f;
#pragma unroll 8
  for (int k = 0; k < KDIM3; ++k) {
    float b0 = Bt[(size_t)k * N_DEPTH + n0];
    float b1 = Bt[(size_t)k * N_DEPTH + n0 + 64];
    float a0 = As[r0][k];               // wave-uniform -> LDS broadcast
    float a1 = As[r1][k];
    acc00 = fmaf(a0, b0, acc00);
    acc01 = fmaf(a0, b1, acc01);
    acc10 = fmaf(a1, b0, acc10);
    acc11 = fmaf(a1, b1, acc11);
  }

  float bv0 = bias[n0], bv1 = bias[n0 + 64];
  int row0 = m0 + r0, row1 = m0 + r1;
  out[(size_t)row0 * N_DEPTH + n0]      = tanhf(acc00 + bv0);
  out[(size_t)row0 * N_DEPTH + n0 + 64] = tanhf(acc01 + bv1);
  out[(size_t)row1 * N_DEPTH + n0]      = tanhf(acc10 + bv0);
  out[(size_t)row1 * N_DEPTH + n0 + 64] = tanhf(acc11 + bv1);
}

// ---------------------------------------------------------------------------
extern "C" void kernel_launch(void* const* d_in, const int* in_sizes, int n_in,
                              void* d_out, int out_size, void* d_ws, size_t ws_size,
                              hipStream_t stream) {
  const float* x     = (const float*)d_in[0];  // [131072, 128] f32
  const int*   split = (const int*)d_in[1];    // [131072] int (sorted)
  const float* W     = (const float*)d_in[2];  // [1408, 128] f32
  const float* bias  = (const float*)d_in[3];  // [128] f32
  float* out = (float*)d_out;                  // [4096, 128] f32

  // Workspace layout (~6.5 MB total)
  float* S       = (float*)d_ws;                                   // 4096*384 f32
  float* Bt      = (float*)((char*)d_ws + (size_t)N_MOLS * KDIM3 * 4);   // 384*128 f32
  int*   offsets = (int*)((char*)Bt + (size_t)KDIM3 * N_DEPTH * 4);      // 4097 int

  wxform_offsets_kernel<<<dim3(192 + 17), dim3(256), 0, stream>>>(W, split, Bt, offsets);
  memb_sums_kernel<<<dim3(N_MOLS), dim3(256), 0, stream>>>(x, offsets, S);
  gemm_bias_tanh_kernel<<<dim3(N_MOLS / GBM), dim3(256), 0, stream>>>(S, Bt, bias, out);
}

// Round 5
// 119.119 us; speedup vs baseline: 1.0394x; 1.0394x over previous
//
#include <hip/hip_runtime.h>
#include <math.h>

#define N_ATOMS 131072
#define N_MOLS  4096
#define DFEAT   128
#define NK      11
#define KDIM3   384          // 3 * DFEAT: [Sr | Sxr | Sxxr] blocks
#define N_DEPTH 128
#define EPS_F   1e-7f
#define MPB     4            // molecules per block (fused kernel)

__constant__ float c_means[NK] = {-1.645f, -1.08f, -0.739f, -0.468f, -0.228f,
                                  0.0f, 0.228f, 0.468f, 0.739f, 1.08f, 1.645f};
__constant__ float c_stds[NK]  = {0.283f, 0.17f, 0.134f, 0.118f, 0.114f,
                                  0.114f, 0.114f, 0.118f, 0.134f, 0.17f, 0.283f};

// Math (verified passing in round 2):
//   o_k(x) = 1 + a_k (x - m_k)^2,  a_k = 0.5 / (s_k^2 * log(s_k*sqrt(2pi))) < 0
//   den(x) = sum_k o_k + EPS = C2 x^2 + C1 x + C0   (always <= -178, rcp-safe)
//   (o_k+EPS)/den = coef0(k)*r + coef1(k)*(x r) + coef2(k)*(x^2 r),  r = 1/den
//   => segment sum needs only Sr, Sxr, Sxxr per (mol, feature);
//      W folds into Bt[384][128] once per launch.

// ---------------------------------------------------------------------------
// Kernel 1: (a) fold W into Bt[384][128]; (b) blocks >= 192 compute molecule
// offsets[0..4096] by binary search over the sorted atom_split.
// ---------------------------------------------------------------------------
__global__ __launch_bounds__(256) void wxform_offsets_kernel(
    const float* __restrict__ W,        // [DFEAT*NK, N_DEPTH]
    const int*   __restrict__ split,    // [N_ATOMS], sorted
    float*       __restrict__ Bt,       // [KDIM3, N_DEPTH]
    int*         __restrict__ offsets) {// [N_MOLS+1]
  const int bid = blockIdx.x;
  const int tid = threadIdx.x;
  if (bid < 192) {
    int t = bid * 256 + tid;            // 0..49151
    int n = t & 127;
    int row = t >> 7;                   // 0..383
    int j = row >> 7;                   // 0..2 (uniform per wave)
    int d = row & 127;
    float acc = 0.0f;
#pragma unroll
    for (int k = 0; k < NK; ++k) {
      float m = c_means[k], s = c_stds[k];
      float a = 0.5f / (s * s * logf(s * 2.5066282746310002f));
      float coef = (j == 2) ? a
                 : (j == 1) ? (-2.0f * a * m)
                            : fmaf(a, m * m, 1.0f + EPS_F);
      acc = fmaf(coef, W[(size_t)(d * NK + k) * N_DEPTH + n], acc);
    }
    Bt[(size_t)row * N_DEPTH + n] = acc;
  } else {
    int t = (bid - 192) * 256 + tid;    // 0..4351
    if (t <= N_MOLS) {
      int lo = 0, hi = N_ATOMS;
      while (lo < hi) { int mid = (lo + hi) >> 1; if (split[mid] < t) lo = mid + 1; else hi = mid; }
      offsets[t] = lo;
    }
  }
}

// ---------------------------------------------------------------------------
// Kernel 2 (fused): per block, MPB=4 molecules.
// Phase A: segment sums Sr/Sxr/Sxxr per feature -> As[4][384] in LDS
//          (8 atom-groups x 32 feature-quads, LDS tree reduce; identical
//           math to the round-2 passing kernel).
// Phase B: out rows = tanh(As @ Bt + b), 2-way K-split per column so every
//          Bt element is read exactly once per block (L2-resident).
// No S intermediate, no third dispatch.
// ---------------------------------------------------------------------------
__global__ __launch_bounds__(256) void fused_sums_gemm_kernel(
    const float* __restrict__ x,        // [N_ATOMS, DFEAT]
    const int*   __restrict__ offsets,  // [N_MOLS+1]
    const float* __restrict__ Bt,       // [KDIM3, N_DEPTH]
    const float* __restrict__ bias,     // [N_DEPTH]
    float*       __restrict__ out) {    // [N_MOLS, N_DEPTH]
  const int tid = threadIdx.x;
  const int m0  = blockIdx.x * MPB;

  __shared__ float As[MPB][KDIM3];      // 6 KB, persists through phase B
  __shared__ float red[8][32][13];      // 13.3 KB, reused as comb in phase B
  float (*comb)[MPB][DFEAT] = (float (*)[MPB][DFEAT])red;  // [2][4][128]

  // Horner coefficients for den = sum_k o_k + EPS (uniform, tiny)
  float C2 = 0.0f, C1 = 0.0f, C0 = 11.0f + EPS_F;
#pragma unroll
  for (int k = 0; k < NK; ++k) {
    float m_ = c_means[k], s_ = c_stds[k];
    float a = 0.5f / (s_ * s_ * logf(s_ * 2.5066282746310002f));
    C2 += a;
    C1 = fmaf(-2.0f * a, m_, C1);
    C0 = fmaf(a, m_ * m_, C0);
  }

  int offs[MPB + 1];
#pragma unroll
  for (int i = 0; i <= MPB; ++i) offs[i] = offsets[m0 + i];

  const int fq = tid & 31;              // feature quad: features fq*4..fq*4+3
  const int g  = tid >> 5;              // atom group 0..7

  // ---------------- Phase A: per-molecule sums ----------------
  for (int i = 0; i < MPB; ++i) {
    float Sr[4]   = {0.f, 0.f, 0.f, 0.f};
    float Sxr[4]  = {0.f, 0.f, 0.f, 0.f};
    float Sxxr[4] = {0.f, 0.f, 0.f, 0.f};

    for (int a = offs[i] + g; a < offs[i + 1]; a += 8) {
      float4 v = *(const float4*)&x[(size_t)a * DFEAT + fq * 4];
      float xv[4] = {v.x, v.y, v.z, v.w};
#pragma unroll
      for (int q = 0; q < 4; ++q) {
        float den = fmaf(fmaf(C2, xv[q], C1), xv[q], C0);
        float r   = __builtin_amdgcn_rcpf(den);   // den <= -178 always
        float u   = xv[q] * r;
        Sr[q]  += r;
        Sxr[q] += u;
        Sxxr[q] = fmaf(xv[q], u, Sxxr[q]);
      }
    }

#pragma unroll
    for (int q = 0; q < 4; ++q) {
      red[g][fq][q * 3 + 0] = Sr[q];
      red[g][fq][q * 3 + 1] = Sxr[q];
      red[g][fq][q * 3 + 2] = Sxxr[q];
    }
    __syncthreads();

    for (int t = tid; t < KDIM3; t += 256) {
      int j = t >> 7;                   // component 0..2
      int f = t & 127;
      int q = f >> 2, fi = f & 3;
      float s = 0.0f;
#pragma unroll
      for (int gg = 0; gg < 8; ++gg) s += red[gg][q][fi * 3 + j];
      As[i][t] = s;
    }
    __syncthreads();                    // red safe to reuse next molecule
  }

  // ---------------- Phase B: [4 x 384] @ Bt[384 x 128] ----------------
  const int n = tid & 127;              // output column
  const int h = tid >> 7;               // k-half 0/1 (uniform per wave)
  const int kbase = h * (KDIM3 / 2);    // 0 or 192

  float acc[MPB] = {0.f, 0.f, 0.f, 0.f};
  for (int kk = 0; kk < KDIM3 / 2; kk += 4) {
    int k = kbase + kk;
    float b0 = Bt[(size_t)(k + 0) * N_DEPTH + n];
    float b1 = Bt[(size_t)(k + 1) * N_DEPTH + n];
    float b2 = Bt[(size_t)(k + 2) * N_DEPTH + n];
    float b3 = Bt[(size_t)(k + 3) * N_DEPTH + n];
#pragma unroll
    for (int i = 0; i < MPB; ++i) {
      float4 av = *(const float4*)&As[i][k];   // wave-uniform -> LDS broadcast
      acc[i] = fmaf(av.x, b0, acc[i]);
      acc[i] = fmaf(av.y, b1, acc[i]);
      acc[i] = fmaf(av.z, b2, acc[i]);
      acc[i] = fmaf(av.w, b3, acc[i]);
    }
  }

  // Combine the two k-halves via LDS (aliases red; all red reads are done).
#pragma unroll
  for (int i = 0; i < MPB; ++i) comb[h][i][n] = acc[i];
  __syncthreads();

#pragma unroll
  for (int off = 0; off < (MPB * DFEAT) / 256; ++off) {  // 2 iters
    int idx = off * 256 + tid;
    int i  = idx >> 7;
    int nn = idx & 127;
    float v = comb[0][i][nn] + comb[1][i][nn] + bias[nn];
    out[(size_t)(m0 + i) * N_DEPTH + nn] = tanhf(v);
  }
}

// ---------------------------------------------------------------------------
extern "C" void kernel_launch(void* const* d_in, const int* in_sizes, int n_in,
                              void* d_out, int out_size, void* d_ws, size_t ws_size,
                              hipStream_t stream) {
  const float* x     = (const float*)d_in[0];  // [131072, 128] f32
  const int*   split = (const int*)d_in[1];    // [131072] int (sorted)
  const float* W     = (const float*)d_in[2];  // [1408, 128] f32
  const float* bias  = (const float*)d_in[3];  // [128] f32
  float* out = (float*)d_out;                  // [4096, 128] f32

  // Workspace: Bt[384*128] f32 then offsets[4097] int (~213 KB total)
  float* Bt      = (float*)d_ws;
  int*   offsets = (int*)((char*)d_ws + (size_t)KDIM3 * N_DEPTH * 4);

  wxform_offsets_kernel<<<dim3(192 + 17), dim3(256), 0, stream>>>(W, split, Bt, offsets);
  fused_sums_gemm_kernel<<<dim3(N_MOLS / MPB), dim3(256), 0, stream>>>(x, offsets, Bt, bias, out);
}